// Round 12
// baseline (4653.102 us; speedup 1.0000x reference)
//
#include <hip/hip_runtime.h>
#include <cstdint>
#include <cstddef>

typedef __bf16 bf16x8 __attribute__((ext_vector_type(8)));
typedef __bf16 bf16x4 __attribute__((ext_vector_type(4)));
typedef float f32x4 __attribute__((ext_vector_type(4)));

__device__ __forceinline__ void gl_lds16(const void* g, void* l) {
  __builtin_amdgcn_global_load_lds(
      (const __attribute__((address_space(1))) void*)g,
      (__attribute__((address_space(3))) void*)l, 16, 0, 0);
}

// ---- weight transpose-convert v2: W fp32 [K,N] -> WT bf16 [N,K] ----
__global__ __launch_bounds__(256) void wconv_t_k(const float* __restrict__ W,
                                                 __bf16* __restrict__ WT,
                                                 int K, int N) {
  __shared__ float tile[64][68];
  const int c0 = blockIdx.x * 64, r0 = blockIdx.y * 64;
  const int t = threadIdx.x;
  const int lr = t >> 4;
  const int lc = (t & 15) * 4;
#pragma unroll
  for (int i = 0; i < 4; ++i) {
    float4 v = *(const float4*)&W[(size_t)(r0 + lr + i * 16) * N + c0 + lc];
    *(float4*)&tile[lr + i * 16][lc] = v;
  }
  __syncthreads();
  const int cr = t >> 4, kb = (t & 15) * 4;
#pragma unroll
  for (int j = 0; j < 4; ++j) {
    const int c = cr + j * 16;
    bf16x4 o;
    o[0] = (__bf16)tile[kb + 0][c];
    o[1] = (__bf16)tile[kb + 1][c];
    o[2] = (__bf16)tile[kb + 2][c];
    o[3] = (__bf16)tile[kb + 3][c];
    *(bf16x4*)&WT[(size_t)(c0 + c) * K + r0 + kb] = o;
  }
}

// ---- rmsnorm fp32 -> bf16 (D=2048, one block per row) ----
__global__ __launch_bounds__(256) void rmsnorm_k(const float* __restrict__ x,
                                                 const float* __restrict__ g,
                                                 __bf16* __restrict__ out) {
  constexpr int D = 2048;
  const int row = blockIdx.x, t = threadIdx.x;
  const float4* xr = (const float4*)(x + (size_t)row * D);
  float4 a = xr[t * 2], b2 = xr[t * 2 + 1];
  float ss = a.x * a.x + a.y * a.y + a.z * a.z + a.w * a.w +
             b2.x * b2.x + b2.y * b2.y + b2.z * b2.z + b2.w * b2.w;
#pragma unroll
  for (int d = 1; d < 64; d <<= 1) ss += __shfl_xor(ss, d, 64);
  __shared__ float red[4];
  if ((t & 63) == 0) red[t >> 6] = ss;
  __syncthreads();
  float rs = rsqrtf((red[0] + red[1] + red[2] + red[3]) * (1.f / D) + 1e-6f);
  const float4* gr = (const float4*)g;
  float4 ga = gr[t * 2], gb = gr[t * 2 + 1];
  bf16x8 o8;
  o8[0] = (__bf16)(a.x * rs * ga.x);
  o8[1] = (__bf16)(a.y * rs * ga.y);
  o8[2] = (__bf16)(a.z * rs * ga.z);
  o8[3] = (__bf16)(a.w * rs * ga.w);
  o8[4] = (__bf16)(b2.x * rs * gb.x);
  o8[5] = (__bf16)(b2.y * rs * gb.y);
  o8[6] = (__bf16)(b2.z * rs * gb.z);
  o8[7] = (__bf16)(b2.w * rs * gb.w);
  *(bf16x8*)(out + (size_t)row * D + t * 8) = o8;
}

// ---- fused: h = p0+p1+res (write), xn = rmsnorm(h)*g (write bf16) ----
__global__ __launch_bounds__(256) void addrms_k(const float* __restrict__ p0,
                                                const float* __restrict__ p1,
                                                const float* __restrict__ res,
                                                const float* __restrict__ g,
                                                float* __restrict__ hout,
                                                __bf16* __restrict__ xnout) {
  constexpr int D = 2048;
  const int row = blockIdx.x, t = threadIdx.x;
  const size_t base = (size_t)row * D;
  float4 h[2];
#pragma unroll
  for (int j = 0; j < 2; ++j) {
    float4 a = ((const float4*)(p0 + base))[t * 2 + j];
    float4 b = ((const float4*)(p1 + base))[t * 2 + j];
    float4 c = ((const float4*)(res + base))[t * 2 + j];
    h[j].x = a.x + b.x + c.x; h[j].y = a.y + b.y + c.y;
    h[j].z = a.z + b.z + c.z; h[j].w = a.w + b.w + c.w;
    ((float4*)(hout + base))[t * 2 + j] = h[j];
  }
  float ss = h[0].x * h[0].x + h[0].y * h[0].y + h[0].z * h[0].z + h[0].w * h[0].w +
             h[1].x * h[1].x + h[1].y * h[1].y + h[1].z * h[1].z + h[1].w * h[1].w;
#pragma unroll
  for (int d = 1; d < 64; d <<= 1) ss += __shfl_xor(ss, d, 64);
  __shared__ float red[4];
  if ((t & 63) == 0) red[t >> 6] = ss;
  __syncthreads();
  float rs = rsqrtf((red[0] + red[1] + red[2] + red[3]) * (1.f / D) + 1e-6f);
  const float4* gr = (const float4*)g;
  float4 ga = gr[t * 2], gb = gr[t * 2 + 1];
  bf16x8 o8;
  o8[0] = (__bf16)(h[0].x * rs * ga.x);
  o8[1] = (__bf16)(h[0].y * rs * ga.y);
  o8[2] = (__bf16)(h[0].z * rs * ga.z);
  o8[3] = (__bf16)(h[0].w * rs * ga.w);
  o8[4] = (__bf16)(h[1].x * rs * gb.x);
  o8[5] = (__bf16)(h[1].y * rs * gb.y);
  o8[6] = (__bf16)(h[1].z * rs * gb.z);
  o8[7] = (__bf16)(h[1].w * rs * gb.w);
  *(bf16x8*)(xnout + base + t * 8) = o8;
}

// ---- reduce: out = p0 + p1 + res (fp32, vectorized) ----
__global__ __launch_bounds__(256) void addred_k(const float* __restrict__ p0,
                                                const float* __restrict__ p1,
                                                const float* __restrict__ res,
                                                float* __restrict__ out, int n4) {
  int i = blockIdx.x * 256 + threadIdx.x;
  const int stride = gridDim.x * 256;
  for (; i < n4; i += stride) {
    float4 a = ((const float4*)p0)[i];
    float4 b = ((const float4*)p1)[i];
    float4 c = ((const float4*)res)[i];
    float4 o = {a.x + b.x + c.x, a.y + b.y + c.y, a.z + b.z + c.z, a.w + b.w + c.w};
    ((float4*)out)[i] = o;
  }
}

// ==== 256x256 GEMM v4 (gemm9): SINGLE-buffered LDS (64KB) -> 2 blocks/CU.
// Per K-tile: reads+MQ(0,*) | lgkm(0)+BAR (tile-t reads done) | stage t+1 |
// MQ(1,*) hides stage | vm(0)+BAR. Intra-block stalls covered by the co-
// resident block's MFMA (TLP, m114). launch_bounds(512,4) pins VGPR<=128.
#define RD_A(HALF) do {                                             \
  const __bf16* aT_ = &As[0] + aoff + (HALF) * 4096;                \
  _Pragma("unroll")                                                 \
  for (int mi = 0; mi < 4; ++mi) {                                  \
    Ar[mi][0] = *(const bf16x8*)(aT_ + mi * 1024 + k0off);          \
    Ar[mi][1] = *(const bf16x8*)(aT_ + mi * 1024 + k1off);          \
  } } while (0)

#define RD_B(NH) do {                                               \
  const __bf16* bT_ = &Bs[0] + boff + (NH) * 2048;                  \
  _Pragma("unroll")                                                 \
  for (int ni = 0; ni < 2; ++ni) {                                  \
    Br[NH][ni][0] = *(const bf16x8*)(bT_ + ni * 1024 + k0off);      \
    Br[NH][ni][1] = *(const bf16x8*)(bT_ + ni * 1024 + k1off);      \
  } } while (0)

#define MQ(MH, NH) do {                                             \
  __builtin_amdgcn_s_setprio(1);                                    \
  _Pragma("unroll")                                                 \
  for (int mi = 0; mi < 4; ++mi) {                                  \
    _Pragma("unroll")                                               \
    for (int ni = 0; ni < 2; ++ni) {                                \
      f32x4& a_ = acc[(MH) * 4 + mi][(NH) * 2 + ni];                \
      a_ = __builtin_amdgcn_mfma_f32_16x16x32_bf16(Ar[mi][0], Br[NH][ni][0], a_, 0, 0, 0); \
      a_ = __builtin_amdgcn_mfma_f32_16x16x32_bf16(Ar[mi][1], Br[NH][ni][1], a_, 0, 0, 0); \
    } }                                                             \
  __builtin_amdgcn_s_setprio(0);                                    \
} while (0)

// MODE: 0 bf16 out; 1 f32 out+res; 2 bf16 silu; 3 bf16 *aux; 4 f32 partial
template <int MODE>
__global__ __launch_bounds__(512, 4) void gemm9_k(
    const __bf16* __restrict__ A, const __bf16* __restrict__ BT,
    const float* __restrict__ res, const __bf16* __restrict__ aux,
    void* __restrict__ Cout, int M, int N, int K, int lda, int cswz) {
  __shared__ alignas(16) __bf16 As[256 * 64];
  __shared__ alignas(16) __bf16 Bs[256 * 64];
  const int tid = threadIdx.x;
  const int lane = tid & 63, w = tid >> 6;
  const int wm = w >> 2, wn = w & 3;
  const int l15 = lane & 15, l16 = lane >> 4;

  const int nbx = gridDim.x, nby = gridDim.y;
  const int nwg = nbx * nby;
  const int bid = blockIdx.y * nbx + blockIdx.x;
  const int swz = (bid & 7) * (nwg >> 3) + (bid >> 3);
  int bx, by;
  if (cswz) { by = swz % nby; bx = swz / nby; }
  else      { bx = swz % nbx; by = swz / nbx; }
  const int m0 = by * 256, n0 = bx * 256;
  const int nkt = K >> 6;

  float* CoutF = (float*)Cout;
  if constexpr (MODE == 4) {
    const int z = blockIdx.z;
    A += (size_t)z * K;
    BT += (size_t)z * K;
    CoutF += (size_t)z * M * N;
  }

  const int srow = tid >> 3;
  const int scole = ((tid & 7) * 8) ^ ((srow & 7) << 3);
  const int brow_i = ((tid >> 8) << 6) + ((tid >> 3) & 31);

  auto stgA = [&](int t, int h) {
    char* dst = (char*)(&As[0]) + h * 8192 + tid * 16;
    const __bf16* src = A + (size_t)(m0 + h * 64 + srow) * lda + t * 64 + scole;
    gl_lds16(src, dst);
    gl_lds16(src + (size_t)128 * lda, dst + 16384);
  };
  auto stgB = [&](int t, int h) {
    const int r = h * 32 + brow_i;
    char* dst = (char*)(&Bs[0]) + r * 128 + (tid & 7) * 16;
    const __bf16* src = BT + (size_t)(n0 + r) * lda + t * 64 + scole;
    gl_lds16(src, dst);
    gl_lds16(src + (size_t)128 * lda, dst + 16384);
  };

  const int rswz = (l15 & 7) << 3;
  const int k0off = (l16 * 8) ^ rswz;
  const int k1off = (32 + l16 * 8) ^ rswz;
  const int aoff = (wm * 128 + l15) * 64;
  const int boff = (wn * 64 + l15) * 64;

  f32x4 acc[8][4] = {};
  bf16x8 Ar[4][2], Br[2][2][2];

  // prologue: stage tile 0 fully, drain, publish
  stgA(0, 0); stgA(0, 1); stgB(0, 0); stgB(0, 1);
  asm volatile("s_waitcnt vmcnt(0)" ::: "memory");
  __builtin_amdgcn_s_barrier();
  __builtin_amdgcn_sched_barrier(0);

  for (int t = 0; t < nkt; ++t) {
    RD_A(0); RD_B(0); RD_B(1);
    MQ(0, 0); MQ(0, 1);
    RD_A(1);
    // all this wave's reads of tile t must COMPLETE before anyone overwrites
    __builtin_amdgcn_sched_barrier(0);
    asm volatile("s_waitcnt lgkmcnt(0)" ::: "memory");
    __builtin_amdgcn_s_barrier();
    __builtin_amdgcn_sched_barrier(0);
    if (t + 1 < nkt) {
      stgA(t + 1, 0); stgA(t + 1, 1); stgB(t + 1, 0); stgB(t + 1, 1);
    }
    MQ(1, 1); MQ(1, 0);  // ~1240 cy: hides stage latency
    __builtin_amdgcn_sched_barrier(0);
    asm volatile("s_waitcnt vmcnt(0)" ::: "memory");
    __builtin_amdgcn_s_barrier();
    __builtin_amdgcn_sched_barrier(0);
  }

  // epilogue
#pragma unroll
  for (int m = 0; m < 8; ++m) {
    const int rowb = m0 + wm * 128 + m * 16 + l16 * 4;
#pragma unroll
    for (int n = 0; n < 4; ++n) {
      const int col = n0 + wn * 64 + n * 16 + l15;
#pragma unroll
      for (int r = 0; r < 4; ++r) {
        const size_t idx = (size_t)(rowb + r) * N + col;
        float v = acc[m][n][r];
        if constexpr (MODE == 1) {
          CoutF[idx] = v + res[idx];
        } else if constexpr (MODE == 2) {
          float s = v / (1.f + __expf(-v));
          ((__bf16*)Cout)[idx] = (__bf16)s;
        } else if constexpr (MODE == 3) {
          ((__bf16*)Cout)[idx] = (__bf16)(v * (float)aux[idx]);
        } else if constexpr (MODE == 4) {
          CoutF[idx] = v;
        } else {
          ((__bf16*)Cout)[idx] = (__bf16)v;
        }
      }
    }
  }
}

// ---- V transpose: qkv(v part) [b,s,h,d] -> VT [bh][d][s] ----
__global__ __launch_bounds__(256) void vtrans_k(const __bf16* __restrict__ qkv,
                                                __bf16* __restrict__ VT) {
  constexpr int S = 2048;
  __shared__ __bf16 tile[64][65];
  const int s0 = blockIdx.x * 64, d0 = blockIdx.y * 64;
  const int bh = blockIdx.z, b = bh >> 4, h = bh & 15;
  const int tx = threadIdx.x & 63, ty = threadIdx.x >> 6;
  const size_t vbase = ((size_t)b * S * 3 + 2) * 2048 + h * 128;
#pragma unroll
  for (int i = 0; i < 16; ++i) {
    int s = ty + i * 4;
    tile[s][tx] = qkv[vbase + (size_t)(s0 + s) * 6144 + d0 + tx];
  }
  __syncthreads();
  const size_t obase = ((size_t)bh * 128 + d0) * S + s0;
#pragma unroll
  for (int i = 0; i < 16; ++i) {
    int d = ty + i * 4;
    VT[obase + (size_t)d * S + tx] = tile[tx][d];
  }
}

// ---- causal flash attention (round-7..11 passing version, unchanged) ----
__global__ __launch_bounds__(512) void attn_k(const __bf16* __restrict__ qkv,
                                              const __bf16* __restrict__ VT,
                                              __bf16* __restrict__ out) {
  constexpr int S = 2048;
  const int bid = blockIdx.x;
  const int bh = (bid & 7) * 4 + ((bid >> 3) & 3);
  const int qb = 15 - (bid >> 5);
  const int b = bh >> 4, h = bh & 15;
  const int q0 = qb * 128;
  const int tid = threadIdx.x, lane = tid & 63, w = tid >> 6;
  const int l15 = lane & 15, l16 = lane >> 4;

  __shared__ __bf16 Ks[64 * 128];
  __shared__ __bf16 Vs[128 * 64];
  __shared__ __bf16 Ps[8][16 * 72];

  const size_t qbase = (size_t)b * S * 6144 + h * 128;
  const size_t kbase = qbase + 2048;
  const size_t vtbase = (size_t)bh * 128 * 2048;

  bf16x8 qf[4];
  {
    const __bf16* qp = qkv + qbase + (size_t)(q0 + w * 16 + l15) * 6144 + l16 * 8;
#pragma unroll
    for (int kc = 0; kc < 4; ++kc) qf[kc] = *(const bf16x8*)(qp + kc * 32);
  }

  f32x4 o[8] = {};
  float mrow[4] = {-1e30f, -1e30f, -1e30f, -1e30f};
  float lrow[4] = {0.f, 0.f, 0.f, 0.f};
  const float sm = 0.08838834764831845f * 1.4426950408889634f;

  int ksrow[2], kscol[2], vsrow[2], vscol[2];
#pragma unroll
  for (int c = 0; c < 2; ++c) {
    int P = (c * 512 + tid) * 16;
    int kr = P >> 8;
    ksrow[c] = kr;
    kscol[c] = ((P & 255) ^ ((kr & 7) << 4)) >> 1;
    int vr = P >> 7;
    vsrow[c] = vr;
    vscol[c] = ((P & 127) ^ ((vr & 7) << 4)) >> 1;
  }
  const int fswz = (l15 & 7) << 3;
  const int qrow_abs = q0 + w * 16 + l16 * 4;

#pragma unroll
  for (int c = 0; c < 2; ++c) {
    int e = (c * 512 + tid) * 8;
    gl_lds16(qkv + kbase + (size_t)ksrow[c] * 6144 + kscol[c], &Ks[e]);
    gl_lds16(VT + vtbase + (size_t)vsrow[c] * 2048 + vscol[c], &Vs[e]);
  }

  const int ntk = 2 * qb + 2;
  for (int kt = 0; kt < ntk; ++kt) {
    const int k0 = kt * 64;
    __syncthreads();

    bf16x8 kreg[2], vreg[2];
    const bool pf = kt + 1 < ntk;
    if (pf) {
      const int kn = k0 + 64;
#pragma unroll
      for (int c = 0; c < 2; ++c)
        kreg[c] = *(const bf16x8*)(qkv + kbase + (size_t)(kn + ksrow[c]) * 6144 + kscol[c]);
#pragma unroll
      for (int c = 0; c < 2; ++c)
        vreg[c] = *(const bf16x8*)(VT + vtbase + (size_t)vsrow[c] * 2048 + kn + vscol[c]);
    }

    f32x4 s4[4];
    __builtin_amdgcn_s_setprio(1);
#pragma unroll
    for (int f = 0; f < 4; ++f) {
      f32x4 accs = {};
#pragma unroll
      for (int kc = 0; kc < 4; ++kc) {
        bf16x8 kf = *(const bf16x8*)&Ks[(f * 16 + l15) * 128 + ((kc * 32 + l16 * 8) ^ fswz)];
        accs = __builtin_amdgcn_mfma_f32_16x16x32_bf16(qf[kc], kf, accs, 0, 0, 0);
      }
      s4[f] = accs;
    }
    __builtin_amdgcn_s_setprio(0);

    float pm[4] = {-1e30f, -1e30f, -1e30f, -1e30f};
    float pvv[4][4];
#pragma unroll
    for (int f = 0; f < 4; ++f) {
      const int key = k0 + f * 16 + l15;
#pragma unroll
      for (int r = 0; r < 4; ++r) {
        float s = s4[f][r] * sm;
        if (key > qrow_abs + r) s = -1e30f;
        pvv[f][r] = s;
        pm[r] = fmaxf(pm[r], s);
      }
    }
#pragma unroll
    for (int d = 1; d < 16; d <<= 1) {
#pragma unroll
      for (int r = 0; r < 4; ++r) pm[r] = fmaxf(pm[r], __shfl_xor(pm[r], d, 64));
    }
    float fac[4], ts[4];
#pragma unroll
    for (int r = 0; r < 4; ++r) {
      float mn = fmaxf(mrow[r], pm[r]);
      fac[r] = exp2f(mrow[r] - mn);
      mrow[r] = mn;
      ts[r] = 0.f;
    }
#pragma unroll
    for (int f = 0; f < 4; ++f) {
#pragma unroll
      for (int r = 0; r < 4; ++r) {
        float p = exp2f(pvv[f][r] - mrow[r]);
        ts[r] += p;
        Ps[w][(l16 * 4 + r) * 72 + f * 16 + l15] = (__bf16)p;
      }
    }
#pragma unroll
    for (int d = 1; d < 16; d <<= 1) {
#pragma unroll
      for (int r = 0; r < 4; ++r) ts[r] += __shfl_xor(ts[r], d, 64);
    }
#pragma unroll
    for (int r = 0; r < 4; ++r) lrow[r] = lrow[r] * fac[r] + ts[r];
#pragma unroll
    for (int n = 0; n < 8; ++n) {
      o[n][0] *= fac[0];
      o[n][1] *= fac[1];
      o[n][2] *= fac[2];
      o[n][3] *= fac[3];
    }
    __builtin_amdgcn_s_setprio(1);
#pragma unroll
    for (int kc = 0; kc < 2; ++kc) {
      bf16x8 pf2 = *(const bf16x8*)&Ps[w][l15 * 72 + kc * 32 + l16 * 8];
#pragma unroll
      for (int n = 0; n < 8; ++n) {
        bf16x8 vf = *(const bf16x8*)&Vs[(n * 16 + l15) * 64 + ((kc * 32 + l16 * 8) ^ fswz)];
        o[n] = __builtin_amdgcn_mfma_f32_16x16x32_bf16(pf2, vf, o[n], 0, 0, 0);
      }
    }
    __builtin_amdgcn_s_setprio(0);
    __syncthreads();

    if (pf) {
#pragma unroll
      for (int c = 0; c < 2; ++c) *(bf16x8*)&Ks[(c * 512 + tid) * 8] = kreg[c];
#pragma unroll
      for (int c = 0; c < 2; ++c) *(bf16x8*)&Vs[(c * 512 + tid) * 8] = vreg[c];
    }
  }

  const int orow = b * S + q0 + w * 16 + l16 * 4;
#pragma unroll
  for (int r = 0; r < 4; ++r) {
    const float inv = 1.f / lrow[r];
#pragma unroll
    for (int n = 0; n < 8; ++n)
      out[(size_t)(orow + r) * 2048 + h * 128 + n * 16 + l15] = (__bf16)(o[n][r] * inv);
  }
}

extern "C" void kernel_launch(void* const* d_in, const int* in_sizes, int n_in,
                              void* d_out, int out_size, void* d_ws, size_t ws_size,
                              hipStream_t stream) {
  (void)in_sizes; (void)n_in; (void)out_size; (void)ws_size;
  const float* x = (const float*)d_in[0];
  const float* w_qkv = (const float*)d_in[1];
  const float* w_out = (const float*)d_in[2];
  const float* w1 = (const float*)d_in[3];
  const float* w2 = (const float*)d_in[4];
  const float* w3 = (const float*)d_in[5];
  const float* g1 = (const float*)d_in[6];
  const float* g2 = (const float*)d_in[7];
  char* ws = (char*)d_ws;

  constexpr int Mr = 4096, D = 2048, DFF = 8192, TD = 6144;

  __bf16* wqkvT = (__bf16*)(ws + 0);
  __bf16* w1T   = (__bf16*)(ws + 0);
  __bf16* woutT = (__bf16*)(ws + 33554432);
  __bf16* qkvb  = (__bf16*)(ws + 41943040);
  __bf16* w3T   = (__bf16*)(ws + 41943040);
  __bf16* w2T   = (__bf16*)(ws + 75497472);
  __bf16* VTb   = (__bf16*)(ws + 92274688);
  __bf16* xn    = (__bf16*)(ws + 109051904);
  __bf16* attn  = (__bf16*)(ws + 125829120);
  float*  hbuf  = (float*)(ws + 142606336);
  __bf16* gbuf  = (__bf16*)(ws + 176160768);
  float*  pO    = (float*)(ws + 176160768);   // out-proj partials (2 x 33.6MB)
  float*  pW0   = (float*)(ws + 0);           // W2 partials (2 x 33.6MB contiguous)

  // 1. weights for attention phase (vectorized 64x64 transpose-convert)
  wconv_t_k<<<dim3(TD / 64, D / 64), 256, 0, stream>>>(w_qkv, wqkvT, D, TD);
  wconv_t_k<<<dim3(D / 64, D / 64), 256, 0, stream>>>(w_out, woutT, D, D);
  // 2. rmsnorm 1
  rmsnorm_k<<<Mr, 256, 0, stream>>>(x, g1, xn);
  // 3. QKV gemm -> bf16 [4096, 6144] (384 blocks, now fully co-resident)
  gemm9_k<0><<<dim3(TD / 256, Mr / 256), 512, 0, stream>>>(xn, wqkvT, nullptr, nullptr, qkvb, Mr, TD, D, D, 1);
  // 4. V transpose per head
  vtrans_k<<<dim3(32, 2, 32), 256, 0, stream>>>(qkvb, VTb);
  // 5. causal flash attention (512 WGs x 512 threads)
  attn_k<<<512, 512, 0, stream>>>(qkvb, VTb, attn);
  // 6. out projection split-K=2 -> partials
  gemm9_k<4><<<dim3(D / 256, Mr / 256, 2), 512, 0, stream>>>(attn, woutT, nullptr, nullptr, pO, Mr, D, D / 2, D, 0);
  // 7. fused: h = pO0+pO1+x -> hbuf; xn = rmsnorm(h)*g2
  addrms_k<<<Mr, 256, 0, stream>>>(pO, pO + (size_t)Mr * D, x, g2, hbuf, xn);
  // 8. convert FFN weights
  wconv_t_k<<<dim3(DFF / 64, D / 64), 256, 0, stream>>>(w1, w1T, D, DFF);
  wconv_t_k<<<dim3(DFF / 64, D / 64), 256, 0, stream>>>(w3, w3T, D, DFF);
  wconv_t_k<<<dim3(D / 64, DFF / 64), 256, 0, stream>>>(w2, w2T, DFF, D);
  // 9. W1 gemm with fused silu -> gbuf bf16 (pO dead now)
  gemm9_k<2><<<dim3(DFF / 256, Mr / 256), 512, 0, stream>>>(xn, w1T, nullptr, nullptr, gbuf, Mr, DFF, D, D, 1);
  // 10. W3 gemm, multiply by silu(a) in epilogue (in-place on gbuf)
  gemm9_k<3><<<dim3(DFF / 256, Mr / 256), 512, 0, stream>>>(xn, w3T, nullptr, gbuf, gbuf, Mr, DFF, D, D, 1);
  // 11. W2 split-K=2 -> pW0 contiguous
  gemm9_k<4><<<dim3(D / 256, Mr / 256, 2), 512, 0, stream>>>(gbuf, w2T, nullptr, nullptr, pW0, Mr, D, DFF / 2, DFF, 0);
  // 12. final reduce + residual -> d_out fp32
  addred_k<<<2048, 256, 0, stream>>>(pW0, pW0 + (size_t)Mr * D, hbuf, (float*)d_out, Mr * D / 4);
}

// Round 13
// 723.864 us; speedup vs baseline: 6.4281x; 6.4281x over previous
//
#include <hip/hip_runtime.h>
#include <cstdint>
#include <cstddef>

typedef __bf16 bf16x8 __attribute__((ext_vector_type(8)));
typedef __bf16 bf16x4 __attribute__((ext_vector_type(4)));
typedef float f32x4 __attribute__((ext_vector_type(4)));

__device__ __forceinline__ void gl_lds16(const void* g, void* l) {
  __builtin_amdgcn_global_load_lds(
      (const __attribute__((address_space(1))) void*)g,
      (__attribute__((address_space(3))) void*)l, 16, 0, 0);
}

// ---- weight transpose-convert v2: W fp32 [K,N] -> WT bf16 [N,K] ----
__global__ __launch_bounds__(256) void wconv_t_k(const float* __restrict__ W,
                                                 __bf16* __restrict__ WT,
                                                 int K, int N) {
  __shared__ float tile[64][68];
  const int c0 = blockIdx.x * 64, r0 = blockIdx.y * 64;
  const int t = threadIdx.x;
  const int lr = t >> 4;
  const int lc = (t & 15) * 4;
#pragma unroll
  for (int i = 0; i < 4; ++i) {
    float4 v = *(const float4*)&W[(size_t)(r0 + lr + i * 16) * N + c0 + lc];
    *(float4*)&tile[lr + i * 16][lc] = v;
  }
  __syncthreads();
  const int cr = t >> 4, kb = (t & 15) * 4;
#pragma unroll
  for (int j = 0; j < 4; ++j) {
    const int c = cr + j * 16;
    bf16x4 o;
    o[0] = (__bf16)tile[kb + 0][c];
    o[1] = (__bf16)tile[kb + 1][c];
    o[2] = (__bf16)tile[kb + 2][c];
    o[3] = (__bf16)tile[kb + 3][c];
    *(bf16x4*)&WT[(size_t)(c0 + c) * K + r0 + kb] = o;
  }
}

// ---- rmsnorm fp32 -> bf16 (D=2048, one block per row) ----
__global__ __launch_bounds__(256) void rmsnorm_k(const float* __restrict__ x,
                                                 const float* __restrict__ g,
                                                 __bf16* __restrict__ out) {
  constexpr int D = 2048;
  const int row = blockIdx.x, t = threadIdx.x;
  const float4* xr = (const float4*)(x + (size_t)row * D);
  float4 a = xr[t * 2], b2 = xr[t * 2 + 1];
  float ss = a.x * a.x + a.y * a.y + a.z * a.z + a.w * a.w +
             b2.x * b2.x + b2.y * b2.y + b2.z * b2.z + b2.w * b2.w;
#pragma unroll
  for (int d = 1; d < 64; d <<= 1) ss += __shfl_xor(ss, d, 64);
  __shared__ float red[4];
  if ((t & 63) == 0) red[t >> 6] = ss;
  __syncthreads();
  float rs = rsqrtf((red[0] + red[1] + red[2] + red[3]) * (1.f / D) + 1e-6f);
  const float4* gr = (const float4*)g;
  float4 ga = gr[t * 2], gb = gr[t * 2 + 1];
  bf16x8 o8;
  o8[0] = (__bf16)(a.x * rs * ga.x);
  o8[1] = (__bf16)(a.y * rs * ga.y);
  o8[2] = (__bf16)(a.z * rs * ga.z);
  o8[3] = (__bf16)(a.w * rs * ga.w);
  o8[4] = (__bf16)(b2.x * rs * gb.x);
  o8[5] = (__bf16)(b2.y * rs * gb.y);
  o8[6] = (__bf16)(b2.z * rs * gb.z);
  o8[7] = (__bf16)(b2.w * rs * gb.w);
  *(bf16x8*)(out + (size_t)row * D + t * 8) = o8;
}

// ---- fused: h = p0+p1+res (write), xn = rmsnorm(h)*g (write bf16) ----
__global__ __launch_bounds__(256) void addrms_k(const float* __restrict__ p0,
                                                const float* __restrict__ p1,
                                                const float* __restrict__ res,
                                                const float* __restrict__ g,
                                                float* __restrict__ hout,
                                                __bf16* __restrict__ xnout) {
  constexpr int D = 2048;
  const int row = blockIdx.x, t = threadIdx.x;
  const size_t base = (size_t)row * D;
  float4 h[2];
#pragma unroll
  for (int j = 0; j < 2; ++j) {
    float4 a = ((const float4*)(p0 + base))[t * 2 + j];
    float4 b = ((const float4*)(p1 + base))[t * 2 + j];
    float4 c = ((const float4*)(res + base))[t * 2 + j];
    h[j].x = a.x + b.x + c.x; h[j].y = a.y + b.y + c.y;
    h[j].z = a.z + b.z + c.z; h[j].w = a.w + b.w + c.w;
    ((float4*)(hout + base))[t * 2 + j] = h[j];
  }
  float ss = h[0].x * h[0].x + h[0].y * h[0].y + h[0].z * h[0].z + h[0].w * h[0].w +
             h[1].x * h[1].x + h[1].y * h[1].y + h[1].z * h[1].z + h[1].w * h[1].w;
#pragma unroll
  for (int d = 1; d < 64; d <<= 1) ss += __shfl_xor(ss, d, 64);
  __shared__ float red[4];
  if ((t & 63) == 0) red[t >> 6] = ss;
  __syncthreads();
  float rs = rsqrtf((red[0] + red[1] + red[2] + red[3]) * (1.f / D) + 1e-6f);
  const float4* gr = (const float4*)g;
  float4 ga = gr[t * 2], gb = gr[t * 2 + 1];
  bf16x8 o8;
  o8[0] = (__bf16)(h[0].x * rs * ga.x);
  o8[1] = (__bf16)(h[0].y * rs * ga.y);
  o8[2] = (__bf16)(h[0].z * rs * ga.z);
  o8[3] = (__bf16)(h[0].w * rs * ga.w);
  o8[4] = (__bf16)(h[1].x * rs * gb.x);
  o8[5] = (__bf16)(h[1].y * rs * gb.y);
  o8[6] = (__bf16)(h[1].z * rs * gb.z);
  o8[7] = (__bf16)(h[1].w * rs * gb.w);
  *(bf16x8*)(xnout + base + t * 8) = o8;
}

// ---- reduce: out = p0 + p1 + res (fp32, vectorized) ----
__global__ __launch_bounds__(256) void addred_k(const float* __restrict__ p0,
                                                const float* __restrict__ p1,
                                                const float* __restrict__ res,
                                                float* __restrict__ out, int n4) {
  int i = blockIdx.x * 256 + threadIdx.x;
  const int stride = gridDim.x * 256;
  for (; i < n4; i += stride) {
    float4 a = ((const float4*)p0)[i];
    float4 b = ((const float4*)p1)[i];
    float4 c = ((const float4*)res)[i];
    float4 o = {a.x + b.x + c.x, a.y + b.y + c.y, a.z + b.z + c.z, a.w + b.w + c.w};
    ((float4*)out)[i] = o;
  }
}

// ==== 256x256 GEMM v3: one region per K-tile, 2 barriers + 2 counted vm
// gates (round-11 passing version, byte-identical). Stage slots: A(X,1)@tile
// X-1 pre; A(X,0),B(X,0),B(X,1)@tile X-2 post. Gates: vm(6) pre-BAR_a
// (retires A(tau,1) for RD_A1); vm(8) pre-BAR_b (retires A/B/B(tau+1)).
#define RD_A(BUF, HALF) do {                                        \
  const __bf16* aT_ = &As[BUF][0] + aoff + (HALF) * 4096;           \
  _Pragma("unroll")                                                 \
  for (int mi = 0; mi < 4; ++mi) {                                  \
    Ar[mi][0] = *(const bf16x8*)(aT_ + mi * 1024 + k0off);          \
    Ar[mi][1] = *(const bf16x8*)(aT_ + mi * 1024 + k1off);          \
  } } while (0)

#define RD_B(BUF, NH) do {                                          \
  const __bf16* bT_ = &Bs[BUF][0] + boff + (NH) * 2048;             \
  _Pragma("unroll")                                                 \
  for (int ni = 0; ni < 2; ++ni) {                                  \
    Br[NH][ni][0] = *(const bf16x8*)(bT_ + ni * 1024 + k0off);      \
    Br[NH][ni][1] = *(const bf16x8*)(bT_ + ni * 1024 + k1off);      \
  } } while (0)

#define MQ0(MH, NH) do {                                            \
  _Pragma("unroll")                                                 \
  for (int mi = 0; mi < 4; ++mi) {                                  \
    _Pragma("unroll")                                               \
    for (int ni = 0; ni < 2; ++ni) {                                \
      f32x4& a_ = acc[(MH) * 4 + mi][(NH) * 2 + ni];                \
      a_ = __builtin_amdgcn_mfma_f32_16x16x32_bf16(Ar[mi][0], Br[NH][ni][0], a_, 0, 0, 0); \
      a_ = __builtin_amdgcn_mfma_f32_16x16x32_bf16(Ar[mi][1], Br[NH][ni][1], a_, 0, 0, 0); \
    } } } while (0)

#define GATE(VM) do {                                               \
  __builtin_amdgcn_sched_barrier(0);                                \
  asm volatile("s_waitcnt vmcnt(" #VM ")" ::: "memory");            \
  __builtin_amdgcn_s_barrier();                                     \
  __builtin_amdgcn_sched_barrier(0);                                \
} while (0)

#define KT3(BUF, PRESTG, POSTSTG, GATEA, GATEEND) do {              \
  RD_A(BUF, 0); RD_B(BUF, 0); RD_B(BUF, 1);                         \
  PRESTG;                                                           \
  GATEA;                                                            \
  __builtin_amdgcn_s_setprio(1);                                    \
  MQ0(0, 0); MQ0(0, 1);                                             \
  RD_A(BUF, 1);                                                     \
  POSTSTG;                                                          \
  MQ0(1, 1); MQ0(1, 0);                                             \
  __builtin_amdgcn_s_setprio(0);                                    \
  GATEEND;                                                          \
} while (0)

// MODE: 0 bf16 out; 1 f32 out+res; 2 bf16 silu; 3 bf16 *aux; 4 f32 partial
template <int MODE>
__global__ __launch_bounds__(512, 2) void gemm8_k(
    const __bf16* __restrict__ A, const __bf16* __restrict__ BT,
    const float* __restrict__ res, const __bf16* __restrict__ aux,
    void* __restrict__ Cout, int M, int N, int K, int lda, int cswz) {
  __shared__ alignas(16) __bf16 As[2][256 * 64];
  __shared__ alignas(16) __bf16 Bs[2][256 * 64];
  const int tid = threadIdx.x;
  const int lane = tid & 63, w = tid >> 6;
  const int wm = w >> 2, wn = w & 3;
  const int l15 = lane & 15, l16 = lane >> 4;

  const int nbx = gridDim.x, nby = gridDim.y;
  const int nwg = nbx * nby;
  const int bid = blockIdx.y * nbx + blockIdx.x;
  const int swz = (bid & 7) * (nwg >> 3) + (bid >> 3);
  int bx, by;
  if (cswz) { by = swz % nby; bx = swz / nby; }
  else      { bx = swz % nbx; by = swz / nbx; }
  const int m0 = by * 256, n0 = bx * 256;
  const int nkt = K >> 6;  // even, >= 4

  float* CoutF = (float*)Cout;
  if constexpr (MODE == 4) {
    const int z = blockIdx.z;
    A += (size_t)z * K;
    BT += (size_t)z * K;
    CoutF += (size_t)z * M * N;
  }

  const int srow = tid >> 3;
  const int scole = ((tid & 7) * 8) ^ ((srow & 7) << 3);
  const int brow_i = ((tid >> 8) << 6) + ((tid >> 3) & 31);

  auto stgA = [&](int t, int h) {
    if (t < nkt) {
      char* dst = (char*)(&As[t & 1][0]) + h * 8192 + tid * 16;
      const __bf16* src = A + (size_t)(m0 + h * 64 + srow) * lda + t * 64 + scole;
      gl_lds16(src, dst);
      gl_lds16(src + (size_t)128 * lda, dst + 16384);
    }
  };
  auto stgB = [&](int t, int h) {
    if (t < nkt) {
      const int r = h * 32 + brow_i;
      char* dst = (char*)(&Bs[t & 1][0]) + r * 128 + (tid & 7) * 16;
      const __bf16* src = BT + (size_t)(n0 + r) * lda + t * 64 + scole;
      gl_lds16(src, dst);
      gl_lds16(src + (size_t)128 * lda, dst + 16384);
    }
  };

  const int rswz = (l15 & 7) << 3;
  const int k0off = (l16 * 8) ^ rswz;
  const int k1off = (32 + l16 * 8) ^ rswz;
  const int aoff = (wm * 128 + l15) * 64;
  const int boff = (wn * 64 + l15) * 64;

  f32x4 acc[8][4] = {};
  bf16x8 Ar[4][2], Br[2][2][2];

  // prologue: A(0,0),B(0,0),B(0,1) first (retired by vm(8)), then the rest
  stgA(0, 0); stgB(0, 0); stgB(0, 1);
  stgA(0, 1); stgA(1, 0); stgB(1, 0); stgB(1, 1);
  asm volatile("s_waitcnt vmcnt(8)" ::: "memory");
  __builtin_amdgcn_s_barrier();
  __builtin_amdgcn_sched_barrier(0);

  int t = 0;
  for (; t + 3 < nkt; t += 2) {
    KT3(0, stgA(t + 1, 1),
        { stgA(t + 2, 0); stgB(t + 2, 0); stgB(t + 2, 1); },
        GATE(6), GATE(8));
    KT3(1, stgA(t + 2, 1),
        { stgA(t + 3, 0); stgB(t + 3, 0); stgB(t + 3, 1); },
        GATE(6), GATE(8));
  }
  // tail u = nkt-2: pre-stage A(nkt-1,1); no post-stages; end gate vm(2)
  KT3(0, stgA(t + 1, 1), (void)0, GATE(6), GATE(2));
  // tail v = nkt-1: no stages; gate vm(0) retires A(v,1); no end gate
  KT3(1, (void)0, (void)0, GATE(0), (void)0);

  // epilogue
#pragma unroll
  for (int m = 0; m < 8; ++m) {
    const int rowb = m0 + wm * 128 + m * 16 + l16 * 4;
#pragma unroll
    for (int n = 0; n < 4; ++n) {
      const int col = n0 + wn * 64 + n * 16 + l15;
#pragma unroll
      for (int r = 0; r < 4; ++r) {
        const size_t idx = (size_t)(rowb + r) * N + col;
        float v = acc[m][n][r];
        if constexpr (MODE == 1) {
          CoutF[idx] = v + res[idx];
        } else if constexpr (MODE == 2) {
          float s = v / (1.f + __expf(-v));
          ((__bf16*)Cout)[idx] = (__bf16)s;
        } else if constexpr (MODE == 3) {
          ((__bf16*)Cout)[idx] = (__bf16)(v * (float)aux[idx]);
        } else if constexpr (MODE == 4) {
          CoutF[idx] = v;
        } else {
          ((__bf16*)Cout)[idx] = (__bf16)v;
        }
      }
    }
  }
}

// ---- V transpose: qkv(v part) [b,s,h,d] -> VT [bh][d][s] ----
__global__ __launch_bounds__(256) void vtrans_k(const __bf16* __restrict__ qkv,
                                                __bf16* __restrict__ VT) {
  constexpr int S = 2048;
  __shared__ __bf16 tile[64][65];
  const int s0 = blockIdx.x * 64, d0 = blockIdx.y * 64;
  const int bh = blockIdx.z, b = bh >> 4, h = bh & 15;
  const int tx = threadIdx.x & 63, ty = threadIdx.x >> 6;
  const size_t vbase = ((size_t)b * S * 3 + 2) * 2048 + h * 128;
#pragma unroll
  for (int i = 0; i < 16; ++i) {
    int s = ty + i * 4;
    tile[s][tx] = qkv[vbase + (size_t)(s0 + s) * 6144 + d0 + tx];
  }
  __syncthreads();
  const size_t obase = ((size_t)bh * 128 + d0) * S + s0;
#pragma unroll
  for (int i = 0; i < 16; ++i) {
    int d = ty + i * 4;
    VT[obase + (size_t)d * S + tx] = tile[tx][d];
  }
}

// ---- causal flash attention (round-7..11 passing version, unchanged) ----
__global__ __launch_bounds__(512) void attn_k(const __bf16* __restrict__ qkv,
                                              const __bf16* __restrict__ VT,
                                              __bf16* __restrict__ out) {
  constexpr int S = 2048;
  const int bid = blockIdx.x;
  const int bh = (bid & 7) * 4 + ((bid >> 3) & 3);
  const int qb = 15 - (bid >> 5);
  const int b = bh >> 4, h = bh & 15;
  const int q0 = qb * 128;
  const int tid = threadIdx.x, lane = tid & 63, w = tid >> 6;
  const int l15 = lane & 15, l16 = lane >> 4;

  __shared__ __bf16 Ks[64 * 128];
  __shared__ __bf16 Vs[128 * 64];
  __shared__ __bf16 Ps[8][16 * 72];

  const size_t qbase = (size_t)b * S * 6144 + h * 128;
  const size_t kbase = qbase + 2048;
  const size_t vtbase = (size_t)bh * 128 * 2048;

  bf16x8 qf[4];
  {
    const __bf16* qp = qkv + qbase + (size_t)(q0 + w * 16 + l15) * 6144 + l16 * 8;
#pragma unroll
    for (int kc = 0; kc < 4; ++kc) qf[kc] = *(const bf16x8*)(qp + kc * 32);
  }

  f32x4 o[8] = {};
  float mrow[4] = {-1e30f, -1e30f, -1e30f, -1e30f};
  float lrow[4] = {0.f, 0.f, 0.f, 0.f};
  const float sm = 0.08838834764831845f * 1.4426950408889634f;

  int ksrow[2], kscol[2], vsrow[2], vscol[2];
#pragma unroll
  for (int c = 0; c < 2; ++c) {
    int P = (c * 512 + tid) * 16;
    int kr = P >> 8;
    ksrow[c] = kr;
    kscol[c] = ((P & 255) ^ ((kr & 7) << 4)) >> 1;
    int vr = P >> 7;
    vsrow[c] = vr;
    vscol[c] = ((P & 127) ^ ((vr & 7) << 4)) >> 1;
  }
  const int fswz = (l15 & 7) << 3;
  const int qrow_abs = q0 + w * 16 + l16 * 4;

#pragma unroll
  for (int c = 0; c < 2; ++c) {
    int e = (c * 512 + tid) * 8;
    gl_lds16(qkv + kbase + (size_t)ksrow[c] * 6144 + kscol[c], &Ks[e]);
    gl_lds16(VT + vtbase + (size_t)vsrow[c] * 2048 + vscol[c], &Vs[e]);
  }

  const int ntk = 2 * qb + 2;
  for (int kt = 0; kt < ntk; ++kt) {
    const int k0 = kt * 64;
    __syncthreads();

    bf16x8 kreg[2], vreg[2];
    const bool pf = kt + 1 < ntk;
    if (pf) {
      const int kn = k0 + 64;
#pragma unroll
      for (int c = 0; c < 2; ++c)
        kreg[c] = *(const bf16x8*)(qkv + kbase + (size_t)(kn + ksrow[c]) * 6144 + kscol[c]);
#pragma unroll
      for (int c = 0; c < 2; ++c)
        vreg[c] = *(const bf16x8*)(VT + vtbase + (size_t)vsrow[c] * 2048 + kn + vscol[c]);
    }

    f32x4 s4[4];
    __builtin_amdgcn_s_setprio(1);
#pragma unroll
    for (int f = 0; f < 4; ++f) {
      f32x4 accs = {};
#pragma unroll
      for (int kc = 0; kc < 4; ++kc) {
        bf16x8 kf = *(const bf16x8*)&Ks[(f * 16 + l15) * 128 + ((kc * 32 + l16 * 8) ^ fswz)];
        accs = __builtin_amdgcn_mfma_f32_16x16x32_bf16(qf[kc], kf, accs, 0, 0, 0);
      }
      s4[f] = accs;
    }
    __builtin_amdgcn_s_setprio(0);

    float pm[4] = {-1e30f, -1e30f, -1e30f, -1e30f};
    float pvv[4][4];
#pragma unroll
    for (int f = 0; f < 4; ++f) {
      const int key = k0 + f * 16 + l15;
#pragma unroll
      for (int r = 0; r < 4; ++r) {
        float s = s4[f][r] * sm;
        if (key > qrow_abs + r) s = -1e30f;
        pvv[f][r] = s;
        pm[r] = fmaxf(pm[r], s);
      }
    }
#pragma unroll
    for (int d = 1; d < 16; d <<= 1) {
#pragma unroll
      for (int r = 0; r < 4; ++r) pm[r] = fmaxf(pm[r], __shfl_xor(pm[r], d, 64));
    }
    float fac[4], ts[4];
#pragma unroll
    for (int r = 0; r < 4; ++r) {
      float mn = fmaxf(mrow[r], pm[r]);
      fac[r] = exp2f(mrow[r] - mn);
      mrow[r] = mn;
      ts[r] = 0.f;
    }
#pragma unroll
    for (int f = 0; f < 4; ++f) {
#pragma unroll
      for (int r = 0; r < 4; ++r) {
        float p = exp2f(pvv[f][r] - mrow[r]);
        ts[r] += p;
        Ps[w][(l16 * 4 + r) * 72 + f * 16 + l15] = (__bf16)p;
      }
    }
#pragma unroll
    for (int d = 1; d < 16; d <<= 1) {
#pragma unroll
      for (int r = 0; r < 4; ++r) ts[r] += __shfl_xor(ts[r], d, 64);
    }
#pragma unroll
    for (int r = 0; r < 4; ++r) lrow[r] = lrow[r] * fac[r] + ts[r];
#pragma unroll
    for (int n = 0; n < 8; ++n) {
      o[n][0] *= fac[0];
      o[n][1] *= fac[1];
      o[n][2] *= fac[2];
      o[n][3] *= fac[3];
    }
    __builtin_amdgcn_s_setprio(1);
#pragma unroll
    for (int kc = 0; kc < 2; ++kc) {
      bf16x8 pf2 = *(const bf16x8*)&Ps[w][l15 * 72 + kc * 32 + l16 * 8];
#pragma unroll
      for (int n = 0; n < 8; ++n) {
        bf16x8 vf = *(const bf16x8*)&Vs[(n * 16 + l15) * 64 + ((kc * 32 + l16 * 8) ^ fswz)];
        o[n] = __builtin_amdgcn_mfma_f32_16x16x32_bf16(pf2, vf, o[n], 0, 0, 0);
      }
    }
    __builtin_amdgcn_s_setprio(0);
    __syncthreads();

    if (pf) {
#pragma unroll
      for (int c = 0; c < 2; ++c) *(bf16x8*)&Ks[(c * 512 + tid) * 8] = kreg[c];
#pragma unroll
      for (int c = 0; c < 2; ++c) *(bf16x8*)&Vs[(c * 512 + tid) * 8] = vreg[c];
    }
  }

  const int orow = b * S + q0 + w * 16 + l16 * 4;
#pragma unroll
  for (int r = 0; r < 4; ++r) {
    const float inv = 1.f / lrow[r];
#pragma unroll
    for (int n = 0; n < 8; ++n)
      out[(size_t)(orow + r) * 2048 + h * 128 + n * 16 + l15] = (__bf16)(o[n][r] * inv);
  }
}

extern "C" void kernel_launch(void* const* d_in, const int* in_sizes, int n_in,
                              void* d_out, int out_size, void* d_ws, size_t ws_size,
                              hipStream_t stream) {
  (void)in_sizes; (void)n_in; (void)out_size; (void)ws_size;
  const float* x = (const float*)d_in[0];
  const float* w_qkv = (const float*)d_in[1];
  const float* w_out = (const float*)d_in[2];
  const float* w1 = (const float*)d_in[3];
  const float* w2 = (const float*)d_in[4];
  const float* w3 = (const float*)d_in[5];
  const float* g1 = (const float*)d_in[6];
  const float* g2 = (const float*)d_in[7];
  char* ws = (char*)d_ws;

  constexpr int Mr = 4096, D = 2048, DFF = 8192, TD = 6144;

  __bf16* wqkvT = (__bf16*)(ws + 0);
  __bf16* w1T   = (__bf16*)(ws + 0);
  __bf16* woutT = (__bf16*)(ws + 33554432);
  __bf16* qkvb  = (__bf16*)(ws + 41943040);
  __bf16* w3T   = (__bf16*)(ws + 41943040);
  __bf16* w2T   = (__bf16*)(ws + 75497472);
  __bf16* VTb   = (__bf16*)(ws + 92274688);
  __bf16* xn    = (__bf16*)(ws + 109051904);
  __bf16* attn  = (__bf16*)(ws + 125829120);
  float*  hbuf  = (float*)(ws + 142606336);
  __bf16* gbuf  = (__bf16*)(ws + 176160768);
  float*  pO    = (float*)(ws + 176160768);   // out-proj partials (2 x 33.6MB)
  float*  pW0   = (float*)(ws + 0);           // W2 partials (2 x 33.6MB contiguous)

  // 1. weights for attention phase (vectorized 64x64 transpose-convert)
  wconv_t_k<<<dim3(TD / 64, D / 64), 256, 0, stream>>>(w_qkv, wqkvT, D, TD);
  wconv_t_k<<<dim3(D / 64, D / 64), 256, 0, stream>>>(w_out, woutT, D, D);
  // 2. rmsnorm 1
  rmsnorm_k<<<Mr, 256, 0, stream>>>(x, g1, xn);
  // 3. QKV gemm -> bf16 [4096, 6144]
  gemm8_k<0><<<dim3(TD / 256, Mr / 256), 512, 0, stream>>>(xn, wqkvT, nullptr, nullptr, qkvb, Mr, TD, D, D, 1);
  // 4. V transpose per head
  vtrans_k<<<dim3(32, 2, 32), 256, 0, stream>>>(qkvb, VTb);
  // 5. causal flash attention (512 WGs x 512 threads)
  attn_k<<<512, 512, 0, stream>>>(qkvb, VTb, attn);
  // 6. out projection split-K=2 -> partials
  gemm8_k<4><<<dim3(D / 256, Mr / 256, 2), 512, 0, stream>>>(attn, woutT, nullptr, nullptr, pO, Mr, D, D / 2, D, 0);
  // 7. fused: h = pO0+pO1+x -> hbuf; xn = rmsnorm(h)*g2
  addrms_k<<<Mr, 256, 0, stream>>>(pO, pO + (size_t)Mr * D, x, g2, hbuf, xn);
  // 8. convert FFN weights
  wconv_t_k<<<dim3(DFF / 64, D / 64), 256, 0, stream>>>(w1, w1T, D, DFF);
  wconv_t_k<<<dim3(DFF / 64, D / 64), 256, 0, stream>>>(w3, w3T, D, DFF);
  wconv_t_k<<<dim3(D / 64, DFF / 64), 256, 0, stream>>>(w2, w2T, DFF, D);
  // 9. W1 gemm with fused silu -> gbuf bf16 (pO dead now)
  gemm8_k<2><<<dim3(DFF / 256, Mr / 256), 512, 0, stream>>>(xn, w1T, nullptr, nullptr, gbuf, Mr, DFF, D, D, 1);
  // 10. W3 gemm, multiply by silu(a) in epilogue (in-place on gbuf)
  gemm8_k<3><<<dim3(DFF / 256, Mr / 256), 512, 0, stream>>>(xn, w3T, nullptr, gbuf, gbuf, Mr, DFF, D, D, 1);
  // 11. W2 split-K=2 -> pW0 contiguous
  gemm8_k<4><<<dim3(D / 256, Mr / 256, 2), 512, 0, stream>>>(gbuf, w2T, nullptr, nullptr, pW0, Mr, D, DFF / 2, DFF, 0);
  // 12. final reduce + residual -> d_out fp32
  addred_k<<<2048, 256, 0, stream>>>(pW0, pW0 + (size_t)Mr * D, hbuf, (float*)d_out, Mr * D / 4);
}